// Round 1
// baseline (4104.927 us; speedup 1.0000x reference)
//
#include <hip/hip_runtime.h>

// Problem constants (from reference)
#define B_DIM   4096
#define IN_DIM  9000
#define OUT_DIM 2048
#define NNZ     200000

// Main-kernel tiling
#define BTILE   8          // batch rows per block
#define THREADS 1024
#define NGROUPS (THREADS / BTILE)   // 128 groups of 8 lanes

// ---------------- CSR build ----------------

__global__ void zero_ints_kernel(int* __restrict__ p, int n) {
    int i = blockIdx.x * blockDim.x + threadIdx.x;
    if (i < n) p[i] = 0;
}

__global__ void hist_kernel(const int* __restrict__ idx, int* __restrict__ cnt) {
    int i = blockIdx.x * blockDim.x + threadIdx.x;
    if (i >= NNZ) return;
    int r = idx[2 * i];
    int c = idx[2 * i + 1];
    if ((unsigned)r < IN_DIM && (unsigned)c < OUT_DIM)
        atomicAdd(&cnt[r], 1);
}

// Single-block exclusive scan over IN_DIM counts -> row_start[IN_DIM+1]
__global__ __launch_bounds__(1024) void scan_kernel(const int* __restrict__ cnt,
                                                    int* __restrict__ row_start) {
    __shared__ int lds_c[IN_DIM];   // 36 KB
    __shared__ int lds_p[1024];     //  4 KB
    int t = threadIdx.x;
    for (int i = t; i < IN_DIM; i += 1024) lds_c[i] = cnt[i];
    __syncthreads();

    const int CH = (IN_DIM + 1023) / 1024;  // 9
    int base = t * CH;
    int partial = 0;
    for (int i = 0; i < CH; ++i) {
        int k = base + i;
        if (k < IN_DIM) partial += lds_c[k];
    }
    lds_p[t] = partial;
    __syncthreads();
    // Hillis-Steele inclusive scan over 1024 partials
    for (int off = 1; off < 1024; off <<= 1) {
        int v = (t >= off) ? lds_p[t - off] : 0;
        __syncthreads();
        lds_p[t] += v;
        __syncthreads();
    }
    int run = (t == 0) ? 0 : lds_p[t - 1];  // exclusive base
    for (int i = 0; i < CH; ++i) {
        int k = base + i;
        if (k < IN_DIM) { row_start[k] = run; run += lds_c[k]; }
    }
    if (t == 1023) row_start[IN_DIM] = lds_p[1023];
}

__global__ void scatter_kernel(const int* __restrict__ idx,
                               const float* __restrict__ w,
                               const int* __restrict__ row_start,
                               int* __restrict__ cur,
                               uint2* __restrict__ entries) {
    int i = blockIdx.x * blockDim.x + threadIdx.x;
    if (i >= NNZ) return;
    int r = idx[2 * i];
    int c = idx[2 * i + 1];
    if ((unsigned)r < IN_DIM && (unsigned)c < OUT_DIM) {
        int pos = row_start[r] + atomicAdd(&cur[r], 1);
        entries[pos] = make_uint2((unsigned)c, __float_as_uint(w[i]));
    }
}

// ---------------- main sparse-matmul ----------------
// Block: BTILE=8 batch rows x all OUT_DIM columns, accumulated in LDS.
// Each group of 8 lanes walks CSR rows r = group, group+128, ...;
// x[b,r] loaded once, reused for all entries of row r (~22 avg).
__global__ __launch_bounds__(THREADS) void spmm_kernel(
    const float* __restrict__ x,
    const float* __restrict__ bias,
    const int*   __restrict__ row_start,
    const uint2* __restrict__ entries,
    float* __restrict__ out) {

    __shared__ float acc[OUT_DIM * BTILE];  // 64 KB

    int t = threadIdx.x;
    for (int i = t; i < OUT_DIM * BTILE; i += THREADS) acc[i] = 0.0f;
    __syncthreads();

    int group  = t >> 3;      // 0..127
    int lane_b = t & 7;       // 0..7
    size_t b = (size_t)blockIdx.x * BTILE + lane_b;
    const float* xrow = x + b * IN_DIM;

    for (int r = group; r < IN_DIM; r += NGROUPS) {
        int s = row_start[r];
        int e = row_start[r + 1];
        if (s == e) continue;
        float xv = xrow[r];   // uncoalesced, but single-use-per-line window fits L1
        for (int j = s; j < e; ++j) {
            uint2 ent = entries[j];
            int   c  = (int)ent.x;
            float wv = __uint_as_float(ent.y);
            // XOR swizzle spreads the 8 lanes of a group across banks and keeps
            // the epilogue read pattern mostly conflict-free.
            atomicAdd(&acc[c * BTILE + (lane_b ^ (c & 7))], wv * xv);
        }
    }
    __syncthreads();

    // Epilogue: fused bias, coalesced stores (64 consecutive c per wave)
    int b_l = t >> 7;         // 0..7
    int c_l = t & 127;        // 0..127
    size_t ob = (size_t)blockIdx.x * BTILE + b_l;
    for (int c0 = 0; c0 < OUT_DIM; c0 += 128) {
        int c = c0 + c_l;
        out[ob * OUT_DIM + c] = acc[c * BTILE + (b_l ^ (c & 7))] + bias[c];
    }
}

// ---------------- launch ----------------

extern "C" void kernel_launch(void* const* d_in, const int* in_sizes, int n_in,
                              void* d_out, int out_size, void* d_ws, size_t ws_size,
                              hipStream_t stream) {
    const float* x    = (const float*)d_in[0];
    const int*   idx  = (const int*)  d_in[1];   // [NNZ,2] as int32 pairs
    const float* w    = (const float*)d_in[2];
    const float* bias = (const float*)d_in[3];
    float* out = (float*)d_out;

    // ws layout: [cnt 9000 | cur 9000 | row_start 9001 | pad | entries NNZ*uint2]
    int* cnt       = (int*)d_ws;
    int* cur       = cnt + IN_DIM;
    int* row_start = cur + IN_DIM;
    size_t ent_off = ((size_t)(2 * IN_DIM + IN_DIM + 1) * sizeof(int) + 15) & ~(size_t)15;
    uint2* entries = (uint2*)((char*)d_ws + ent_off);

    // 1) zero counters
    {
        int n = 2 * IN_DIM;
        zero_ints_kernel<<<(n + 255) / 256, 256, 0, stream>>>(cnt, n);
    }
    // 2) histogram by row
    hist_kernel<<<(NNZ + 255) / 256, 256, 0, stream>>>(idx, cnt);
    // 3) exclusive scan -> row_start
    scan_kernel<<<1, 1024, 0, stream>>>(cnt, row_start);
    // 4) scatter entries into CSR order
    scatter_kernel<<<(NNZ + 255) / 256, 256, 0, stream>>>(idx, w, row_start, cur, entries);
    // 5) main spmm + bias
    spmm_kernel<<<B_DIM / BTILE, THREADS, 0, stream>>>(x, bias, row_start, entries, out);
}

// Round 2
// 4099.696 us; speedup vs baseline: 1.0013x; 1.0013x over previous
//
#include <hip/hip_runtime.h>

// Problem constants (from reference)
#define B_DIM   4096
#define IN_DIM  9000
#define OUT_DIM 2048
#define NNZ     200000

// Main-kernel tiling
#define BTILE   8            // batch rows per block
#define THREADS 1024
#define ETEAM   128          // threads per batch row (e_l)
#define EPT     4            // entries per thread per iteration
#define EITER   (ETEAM * EPT)          // 512 entries per block-iteration
#define FULL_ITERS (NNZ / EITER)       // 390
#define TAIL_BASE  (FULL_ITERS * EITER)

// ---------------- CSR build (sort entries by row r for x-gather locality) ----

__global__ void zero_ints_kernel(int* __restrict__ p, int n) {
    int i = blockIdx.x * blockDim.x + threadIdx.x;
    if (i < n) p[i] = 0;
}

__global__ void hist_kernel(const int* __restrict__ idx, int* __restrict__ cnt) {
    int i = blockIdx.x * blockDim.x + threadIdx.x;
    if (i >= NNZ) return;
    int r = idx[2 * i];
    int c = idx[2 * i + 1];
    if ((unsigned)r < IN_DIM && (unsigned)c < OUT_DIM)
        atomicAdd(&cnt[r], 1);
}

// Single-block exclusive scan over IN_DIM counts -> row_start[IN_DIM+1]
__global__ __launch_bounds__(1024) void scan_kernel(const int* __restrict__ cnt,
                                                    int* __restrict__ row_start) {
    __shared__ int lds_c[IN_DIM];   // 36 KB
    __shared__ int lds_p[1024];     //  4 KB
    int t = threadIdx.x;
    for (int i = t; i < IN_DIM; i += 1024) lds_c[i] = cnt[i];
    __syncthreads();

    const int CH = (IN_DIM + 1023) / 1024;  // 9
    int base = t * CH;
    int partial = 0;
    for (int i = 0; i < CH; ++i) {
        int k = base + i;
        if (k < IN_DIM) partial += lds_c[k];
    }
    lds_p[t] = partial;
    __syncthreads();
    for (int off = 1; off < 1024; off <<= 1) {
        int v = (t >= off) ? lds_p[t - off] : 0;
        __syncthreads();
        lds_p[t] += v;
        __syncthreads();
    }
    int run = (t == 0) ? 0 : lds_p[t - 1];  // exclusive base
    for (int i = 0; i < CH; ++i) {
        int k = base + i;
        if (k < IN_DIM) { row_start[k] = run; run += lds_c[k]; }
    }
    if (t == 1023) row_start[IN_DIM] = lds_p[1023];
}

// entries[pos] = { rc = (r<<11)|c , bits(w) }  (8 B/entry, r-sorted)
__global__ void scatter_kernel(const int* __restrict__ idx,
                               const float* __restrict__ w,
                               const int* __restrict__ row_start,
                               int* __restrict__ cur,
                               uint2* __restrict__ entries) {
    int i = blockIdx.x * blockDim.x + threadIdx.x;
    if (i >= NNZ) return;
    int r = idx[2 * i];
    int c = idx[2 * i + 1];
    if ((unsigned)r < IN_DIM && (unsigned)c < OUT_DIM) {
        int pos = row_start[r] + atomicAdd(&cur[r], 1);
        entries[pos] = make_uint2(((unsigned)r << 11) | (unsigned)c,
                                  __float_as_uint(w[i]));
    }
}

// ---------------- main sparse-matmul ----------------
// Block: BTILE=8 batch rows x all OUT_DIM columns, LDS accumulator acc[b][c].
// Flat, constant-trip-count walk over r-sorted entries:
//   - team of 128 threads per b; wave lanes load CONSECUTIVE entries (coalesced)
//   - x[b,r] gather is near-broadcast (sorted r: ~6 distinct r per 256 entries)
//   - 4 independent ds_add chains per thread per iteration -> pipelineable
__global__ __launch_bounds__(THREADS) void spmm_kernel(
    const float* __restrict__ x,
    const float* __restrict__ bias,
    const uint2* __restrict__ entries,
    float* __restrict__ out) {

    __shared__ float acc[BTILE * OUT_DIM];  // 64 KB -> 2 blocks/CU

    int t = threadIdx.x;
    float4* accv = (float4*)acc;
    for (int i = t; i < (BTILE * OUT_DIM) / 4; i += THREADS)
        accv[i] = make_float4(0.f, 0.f, 0.f, 0.f);
    __syncthreads();

    const int b_l = t >> 7;        // 0..7
    const int e_l = t & 127;       // 0..127
    const float* __restrict__ xrow =
        x + ((size_t)blockIdx.x * BTILE + b_l) * IN_DIM;
    float* __restrict__ accb = acc + b_l * OUT_DIM;

    const uint4* __restrict__ ent4 = (const uint4*)entries;  // 2 entries / uint4

    for (int it = 0; it < FULL_ITERS; ++it) {
        int j2 = (it * EITER + e_l * EPT) >> 1;  // uint4 index
        uint4 p0 = ent4[j2];
        uint4 p1 = ent4[j2 + 1];
        // 4 independent gather+MAC chains
        float xv0 = xrow[p0.x >> 11];
        float xv1 = xrow[p0.z >> 11];
        float xv2 = xrow[p1.x >> 11];
        float xv3 = xrow[p1.z >> 11];
        atomicAdd(&accb[p0.x & 2047], __uint_as_float(p0.y) * xv0);
        atomicAdd(&accb[p0.z & 2047], __uint_as_float(p0.w) * xv1);
        atomicAdd(&accb[p1.x & 2047], __uint_as_float(p1.y) * xv2);
        atomicAdd(&accb[p1.z & 2047], __uint_as_float(p1.w) * xv3);
    }
    // tail: entries TAIL_BASE..NNZ-1
    for (int j = TAIL_BASE + e_l; j < NNZ; j += ETEAM) {
        uint2 e = entries[j];
        atomicAdd(&accb[e.x & 2047], __uint_as_float(e.y) * xrow[e.x >> 11]);
    }
    __syncthreads();

    // Epilogue: fused bias, fully coalesced
    size_t ob0 = (size_t)blockIdx.x * BTILE;
    for (int i = t; i < BTILE * OUT_DIM; i += THREADS) {
        int b = i >> 11;        // /OUT_DIM
        int c = i & 2047;
        out[(ob0 + b) * OUT_DIM + c] = acc[i] + bias[c];
    }
}

// ---------------- launch ----------------

extern "C" void kernel_launch(void* const* d_in, const int* in_sizes, int n_in,
                              void* d_out, int out_size, void* d_ws, size_t ws_size,
                              hipStream_t stream) {
    const float* x    = (const float*)d_in[0];
    const int*   idx  = (const int*)  d_in[1];   // [NNZ,2] as int32 pairs
    const float* w    = (const float*)d_in[2];
    const float* bias = (const float*)d_in[3];
    float* out = (float*)d_out;

    // ws layout: [cnt 9000 | cur 9000 | row_start 9001 | pad | entries NNZ*uint2]
    int* cnt       = (int*)d_ws;
    int* cur       = cnt + IN_DIM;
    int* row_start = cur + IN_DIM;
    size_t ent_off = ((size_t)(2 * IN_DIM + IN_DIM + 1) * sizeof(int) + 15) & ~(size_t)15;
    uint2* entries = (uint2*)((char*)d_ws + ent_off);

    {
        int n = 2 * IN_DIM;
        zero_ints_kernel<<<(n + 255) / 256, 256, 0, stream>>>(cnt, n);
    }
    hist_kernel<<<(NNZ + 255) / 256, 256, 0, stream>>>(idx, cnt);
    scan_kernel<<<1, 1024, 0, stream>>>(cnt, row_start);
    scatter_kernel<<<(NNZ + 255) / 256, 256, 0, stream>>>(idx, w, row_start, cur, entries);
    spmm_kernel<<<B_DIM / BTILE, THREADS, 0, stream>>>(x, bias, entries, out);
}

// Round 3
// 406.147 us; speedup vs baseline: 10.1070x; 10.0941x over previous
//
#include <hip/hip_runtime.h>

// Problem constants (from reference)
#define B_DIM   4096
#define IN_DIM  9000
#define OUT_DIM 2048
#define NNZ     200000

// Tiling
#define BTILE   8                 // batch rows per block (and per-thread acc)
#define THREADS 1024
#define SEGLEN  1360              // r-rows per LDS segment
#define NSEG    7                 // ceil(9000/1360): 6*1360=8160, last=840
#define NKEY    (NSEG * OUT_DIM)  // 14336 (seg,col) buckets
#define XPAD    12                // LDS floats per r-row: 48B stride, 16B-aligned

// ---------------- bucket build: sort entries by (r-segment, column) --------

__global__ void zero_ints_kernel(int* __restrict__ p, int n) {
    int i = blockIdx.x * blockDim.x + threadIdx.x;
    if (i < n) p[i] = 0;
}

__global__ void hist_kernel(const int* __restrict__ idx, int* __restrict__ cnt) {
    int i = blockIdx.x * blockDim.x + threadIdx.x;
    if (i >= NNZ) return;
    int r = idx[2 * i];
    int c = idx[2 * i + 1];
    if ((unsigned)r < IN_DIM && (unsigned)c < OUT_DIM) {
        int seg = r / SEGLEN;
        atomicAdd(&cnt[seg * OUT_DIM + c], 1);
    }
}

// Single-block exclusive scan over NKEY counts -> key_start[NKEY+1]
__global__ __launch_bounds__(1024) void scan_kernel(const int* __restrict__ cnt,
                                                    int* __restrict__ key_start) {
    __shared__ int lds_c[NKEY];    // 57 KB
    __shared__ int lds_p[1024];    //  4 KB
    int t = threadIdx.x;
    for (int i = t; i < NKEY; i += 1024) lds_c[i] = cnt[i];
    __syncthreads();

    const int CH = NKEY / 1024;    // 14
    int base = t * CH;
    int partial = 0;
    for (int i = 0; i < CH; ++i) partial += lds_c[base + i];
    lds_p[t] = partial;
    __syncthreads();
    for (int off = 1; off < 1024; off <<= 1) {
        int v = (t >= off) ? lds_p[t - off] : 0;
        __syncthreads();
        lds_p[t] += v;
        __syncthreads();
    }
    int run = (t == 0) ? 0 : lds_p[t - 1];   // exclusive base
    for (int i = 0; i < CH; ++i) {
        key_start[base + i] = run;
        run += lds_c[base + i];
    }
    if (t == 1023) key_start[NKEY] = lds_p[1023];
}

// entries[pos] = { r_local , bits(w) }, bucketed by (seg, c)
__global__ void scatter_kernel(const int* __restrict__ idx,
                               const float* __restrict__ w,
                               const int* __restrict__ key_start,
                               int* __restrict__ cur,
                               uint2* __restrict__ entries) {
    int i = blockIdx.x * blockDim.x + threadIdx.x;
    if (i >= NNZ) return;
    int r = idx[2 * i];
    int c = idx[2 * i + 1];
    if ((unsigned)r < IN_DIM && (unsigned)c < OUT_DIM) {
        int seg = r / SEGLEN;
        int key = seg * OUT_DIM + c;
        int pos = key_start[key] + atomicAdd(&cur[key], 1);
        entries[pos] = make_uint2((unsigned)(r - seg * SEGLEN),
                                  __float_as_uint(w[i]));
    }
}

// ---------------- main sparse-matmul: CSC walk, register accumulate --------
// Block: 8 batch rows x 2048 columns. Thread t owns columns {t, t+1024},
// 8 register accumulators each. Per r-segment: stage x[b][rbase..] into LDS
// transposed (xs[r*12+b], 16B-aligned rows) then walk the (seg,col) entry
// lists: 2 x ds_read_b128 + 8 FMA per entry. NO atomics anywhere.
__global__ __launch_bounds__(THREADS, 8) void spmm_kernel(
    const float* __restrict__ x,
    const float* __restrict__ bias,
    const int*   __restrict__ key_start,
    const uint2* __restrict__ entries,
    float* __restrict__ out) {

    __shared__ float xs[SEGLEN * XPAD];   // 65280 B

    const int t = threadIdx.x;
    const size_t b0 = (size_t)blockIdx.x * BTILE;
    const int c0 = t;
    const int c1 = t + THREADS;

    float acc0[BTILE], acc1[BTILE];
#pragma unroll
    for (int b = 0; b < BTILE; ++b) { acc0[b] = 0.f; acc1[b] = 0.f; }

    for (int seg = 0; seg < NSEG; ++seg) {
        const int rbase = seg * SEGLEN;
        const int rlen  = (IN_DIM - rbase < SEGLEN) ? (IN_DIM - rbase) : SEGLEN;
        __syncthreads();
        // stage x rows (coalesced global reads; strided LDS writes)
#pragma unroll
        for (int b = 0; b < BTILE; ++b) {
            const float* __restrict__ src = x + (b0 + b) * IN_DIM + rbase;
            for (int r = t; r < rlen; r += THREADS)
                xs[r * XPAD + b] = src[r];
        }
        __syncthreads();

        // column c0
        {
            int s = key_start[seg * OUT_DIM + c0];
            int e = key_start[seg * OUT_DIM + c0 + 1];
            int j = s;
            uint2 en = (j < e) ? entries[j] : make_uint2(0u, 0u);
            while (j < e) {
                uint2 cur_e = en;
                ++j;
                if (j < e) en = entries[j];   // 1-ahead prefetch
                float wv = __uint_as_float(cur_e.y);
                const float4* xr = (const float4*)(xs + cur_e.x * XPAD);
                float4 lo = xr[0];
                float4 hi = xr[1];
                acc0[0] = fmaf(wv, lo.x, acc0[0]);
                acc0[1] = fmaf(wv, lo.y, acc0[1]);
                acc0[2] = fmaf(wv, lo.z, acc0[2]);
                acc0[3] = fmaf(wv, lo.w, acc0[3]);
                acc0[4] = fmaf(wv, hi.x, acc0[4]);
                acc0[5] = fmaf(wv, hi.y, acc0[5]);
                acc0[6] = fmaf(wv, hi.z, acc0[6]);
                acc0[7] = fmaf(wv, hi.w, acc0[7]);
            }
        }
        // column c1
        {
            int s = key_start[seg * OUT_DIM + c1];
            int e = key_start[seg * OUT_DIM + c1 + 1];
            int j = s;
            uint2 en = (j < e) ? entries[j] : make_uint2(0u, 0u);
            while (j < e) {
                uint2 cur_e = en;
                ++j;
                if (j < e) en = entries[j];
                float wv = __uint_as_float(cur_e.y);
                const float4* xr = (const float4*)(xs + cur_e.x * XPAD);
                float4 lo = xr[0];
                float4 hi = xr[1];
                acc1[0] = fmaf(wv, lo.x, acc1[0]);
                acc1[1] = fmaf(wv, lo.y, acc1[1]);
                acc1[2] = fmaf(wv, lo.z, acc1[2]);
                acc1[3] = fmaf(wv, lo.w, acc1[3]);
                acc1[4] = fmaf(wv, hi.x, acc1[4]);
                acc1[5] = fmaf(wv, hi.y, acc1[5]);
                acc1[6] = fmaf(wv, hi.z, acc1[6]);
                acc1[7] = fmaf(wv, hi.w, acc1[7]);
            }
        }
    }

    // epilogue: fused bias, fully coalesced (64 consecutive c per wave)
    const float bi0 = bias[c0];
    const float bi1 = bias[c1];
#pragma unroll
    for (int b = 0; b < BTILE; ++b) {
        out[(b0 + b) * OUT_DIM + c0] = acc0[b] + bi0;
        out[(b0 + b) * OUT_DIM + c1] = acc1[b] + bi1;
    }
}

// ---------------- launch ----------------

extern "C" void kernel_launch(void* const* d_in, const int* in_sizes, int n_in,
                              void* d_out, int out_size, void* d_ws, size_t ws_size,
                              hipStream_t stream) {
    const float* x    = (const float*)d_in[0];
    const int*   idx  = (const int*)  d_in[1];   // [NNZ,2] int pairs
    const float* w    = (const float*)d_in[2];
    const float* bias = (const float*)d_in[3];
    float* out = (float*)d_out;

    // ws layout: [cnt NKEY | cur NKEY | key_start NKEY+1 | pad | entries NNZ*uint2]
    int* cnt       = (int*)d_ws;
    int* cur       = cnt + NKEY;
    int* key_start = cur + NKEY;
    size_t ent_off = ((size_t)(2 * NKEY + NKEY + 1) * sizeof(int) + 15) & ~(size_t)15;
    uint2* entries = (uint2*)((char*)d_ws + ent_off);

    {
        int n = 2 * NKEY;
        zero_ints_kernel<<<(n + 255) / 256, 256, 0, stream>>>(cnt, n);
    }
    hist_kernel<<<(NNZ + 255) / 256, 256, 0, stream>>>(idx, cnt);
    scan_kernel<<<1, 1024, 0, stream>>>(cnt, key_start);
    scatter_kernel<<<(NNZ + 255) / 256, 256, 0, stream>>>(idx, w, key_start, cur, entries);
    spmm_kernel<<<B_DIM / BTILE, THREADS, 0, stream>>>(x, bias, key_start, entries, out);
}